// Round 1
// baseline (5337.480 us; speedup 1.0000x reference)
//
#include <hip/hip_runtime.h>
#include <math.h>

#define BB 4
#define TT 784
#define GG 28
#define EE 768
#define HDIM 3072
#define NHEAD 12
#define NLAYER 6

// ---------------------------------------------------------------- reductions
__device__ __forceinline__ float block_reduce_sum256(float v, volatile float* sb) {
    #pragma unroll
    for (int m = 1; m < 64; m <<= 1) v += __shfl_xor(v, m, 64);
    int wave = threadIdx.x >> 6;
    if ((threadIdx.x & 63) == 0) sb[wave] = v;
    __syncthreads();
    return sb[0] + sb[1] + sb[2] + sb[3];
}

// ---------------------------------------------------------------- patchify
__global__ __launch_bounds__(256) void patchify_kernel(const float* __restrict__ x,
                                                       float* __restrict__ P) {
    int idx = blockIdx.x * blockDim.x + threadIdx.x;
    const int total = BB * TT * EE;
    if (idx >= total) return;
    int k = idx % EE;
    int t = (idx / EE) % TT;
    int b = idx / (EE * TT);
    int c = k >> 8;
    int rem = k & 255;
    int p1 = rem >> 4;
    int p2 = rem & 15;
    int g1 = t / GG, g2 = t % GG;
    int hh = g1 * 16 + p1, ww = g2 * 16 + p2;
    P[idx] = x[((b * 448 + hh) * 448 + ww) * 3 + c];
}

// ---------------------------------------------------------------- pos add
__global__ __launch_bounds__(256) void addpos_kernel(float* __restrict__ h,
                                                     const float* __restrict__ pos) {
    int idx = blockIdx.x * blockDim.x + threadIdx.x;
    const int total = BB * TT * EE;
    if (idx >= total) return;
    int e = idx % EE;
    int t = (idx / EE) % TT;
    h[idx] += pos[t * EE + e];
}

// ---------------------------------------------------------------- layernorm (768 cols)
__global__ __launch_bounds__(256) void ln_kernel(const float* __restrict__ X,
                                                 const float* __restrict__ g,
                                                 const float* __restrict__ bt,
                                                 float* __restrict__ Y) {
    __shared__ float sb1[4];
    __shared__ float sb2[4];
    int row = blockIdx.x;
    int tid = threadIdx.x;
    const float* x = X + (size_t)row * EE;
    float v0 = x[tid], v1 = x[tid + 256], v2 = x[tid + 512];
    float s = block_reduce_sum256(v0 + v1 + v2, sb1);
    float mean = s * (1.0f / 768.0f);
    float d0 = v0 - mean, d1 = v1 - mean, d2 = v2 - mean;
    __syncthreads();
    float ss = block_reduce_sum256(d0 * d0 + d1 * d1 + d2 * d2, sb2);
    float rstd = rsqrtf(ss * (1.0f / 768.0f) + 1e-5f);
    float* y = Y + (size_t)row * EE;
    y[tid]       = d0 * rstd * g[tid]       + bt[tid];
    y[tid + 256] = d1 * rstd * g[tid + 256] + bt[tid + 256];
    y[tid + 512] = d2 * rstd * g[tid + 512] + bt[tid + 512];
}

// ---------------------------------------------------------------- GEMM: C = A @ W^T + bias (+R) (+gelu)
// A: [M,K] row-major, W: [N,K] row-major. M,N multiples of 64, K multiple of 16.
// NOTE: R and C may alias (residual in-place) -> no __restrict__ on them.
__global__ __launch_bounds__(256) void gemm_kernel(const float* __restrict__ A,
                                                   const float* __restrict__ W,
                                                   const float* __restrict__ bias,
                                                   const float* R, float* C,
                                                   int M, int N, int K, int act) {
    __shared__ float As[16][68];   // [kk][row-in-tile]
    __shared__ float Ws[16][68];   // [kk][col-in-tile]
    int tid = threadIdx.x;
    int tx = tid & 15, ty = tid >> 4;
    int m0 = blockIdx.y << 6, n0 = blockIdx.x << 6;
    int lr = tid >> 2;            // 0..63
    int lc4 = (tid & 3) << 2;     // 0,4,8,12
    float acc[4][4] = {};
    const float* Arow = A + (size_t)(m0 + lr) * K + lc4;
    const float* Wrow = W + (size_t)(n0 + lr) * K + lc4;
    for (int k0 = 0; k0 < K; k0 += 16) {
        float4 av = *(const float4*)(Arow + k0);
        float4 wv = *(const float4*)(Wrow + k0);
        __syncthreads();
        As[lc4 + 0][lr] = av.x; As[lc4 + 1][lr] = av.y;
        As[lc4 + 2][lr] = av.z; As[lc4 + 3][lr] = av.w;
        Ws[lc4 + 0][lr] = wv.x; Ws[lc4 + 1][lr] = wv.y;
        Ws[lc4 + 2][lr] = wv.z; Ws[lc4 + 3][lr] = wv.w;
        __syncthreads();
        #pragma unroll
        for (int kk = 0; kk < 16; kk++) {
            float4 a4 = *(const float4*)&As[kk][ty * 4];
            float4 b4 = *(const float4*)&Ws[kk][tx * 4];
            float aa[4] = {a4.x, a4.y, a4.z, a4.w};
            float bb[4] = {b4.x, b4.y, b4.z, b4.w};
            #pragma unroll
            for (int i = 0; i < 4; i++)
                #pragma unroll
                for (int j = 0; j < 4; j++)
                    acc[i][j] = fmaf(aa[i], bb[j], acc[i][j]);
        }
    }
    #pragma unroll
    for (int i = 0; i < 4; i++) {
        int row = m0 + ty * 4 + i;
        int col = n0 + tx * 4;
        float vb[4];
        #pragma unroll
        for (int j = 0; j < 4; j++) vb[j] = acc[i][j] + bias[col + j];
        if (R) {
            float4 r4 = *(const float4*)&R[(size_t)row * N + col];
            vb[0] += r4.x; vb[1] += r4.y; vb[2] += r4.z; vb[3] += r4.w;
        }
        if (act == 1) {
            #pragma unroll
            for (int j = 0; j < 4; j++)
                vb[j] = 0.5f * vb[j] * (1.0f + erff(vb[j] * 0.70710678118654752f));
        }
        *(float4*)&C[(size_t)row * N + col] = make_float4(vb[0], vb[1], vb[2], vb[3]);
    }
}

// ---------------------------------------------------------------- flash attention with local-mask (masked OUT)
// qkv: [B*T, 3E]; O: [B*T, E]. grid: (13 q-tiles, B*NH). block 256.
__global__ __launch_bounds__(256) void attn_kernel(const float* __restrict__ qkv,
                                                   float* __restrict__ O) {
    __shared__ float Qs[64][68];   // [d][r]
    __shared__ float Ks[64][68];   // [d][c]; reused as P[c][r]
    __shared__ float Vs[64][68];   // [c][d]
    int tid = threadIdx.x;
    int tx = tid & 15, ty = tid >> 4;
    int bh = blockIdx.y;
    int b = bh / NHEAD, hh = bh % NHEAD;
    int q0 = blockIdx.x * 64;

    // load Q tile (transposed)
    #pragma unroll
    for (int p = 0; p < 4; p++) {
        int f4 = tid + p * 256;       // 0..1023
        int r = f4 >> 4;              // 0..63
        int d4 = (f4 & 15) << 2;      // 0..60
        int qg = q0 + r;
        float4 qv = make_float4(0.f, 0.f, 0.f, 0.f);
        if (qg < TT)
            qv = *(const float4*)&qkv[(size_t)(b * TT + qg) * 2304 + hh * 64 + d4];
        Qs[d4 + 0][r] = qv.x; Qs[d4 + 1][r] = qv.y;
        Qs[d4 + 2][r] = qv.z; Qs[d4 + 3][r] = qv.w;
    }

    float o_acc[4][4] = {};
    float m_run[4], l_run[4];
    int qr_[4], qc_[4], qg_[4];
    #pragma unroll
    for (int i = 0; i < 4; i++) {
        m_run[i] = -1e30f; l_run[i] = 0.0f;
        qg_[i] = q0 + ty * 4 + i;
        qr_[i] = qg_[i] / GG;
        qc_[i] = qg_[i] % GG;
    }

    for (int k0 = 0; k0 < TT; k0 += 64) {
        __syncthreads();   // prev PV reads done
        #pragma unroll
        for (int p = 0; p < 4; p++) {
            int f4 = tid + p * 256;
            int r = f4 >> 4;
            int d4 = (f4 & 15) << 2;
            int kg = k0 + r;
            float4 kv = make_float4(0.f, 0.f, 0.f, 0.f);
            float4 vv = make_float4(0.f, 0.f, 0.f, 0.f);
            if (kg < TT) {
                size_t base = (size_t)(b * TT + kg) * 2304 + hh * 64 + d4;
                kv = *(const float4*)&qkv[base + 768];
                vv = *(const float4*)&qkv[base + 1536];
            }
            Ks[d4 + 0][r] = kv.x; Ks[d4 + 1][r] = kv.y;
            Ks[d4 + 2][r] = kv.z; Ks[d4 + 3][r] = kv.w;
            *(float4*)&Vs[r][d4] = vv;
        }
        __syncthreads();

        // S = Q K^T (per-thread 4x4)
        float s[4][4] = {};
        #pragma unroll 8
        for (int d = 0; d < 64; d++) {
            float4 a4 = *(const float4*)&Qs[d][ty * 4];
            float4 b4 = *(const float4*)&Ks[d][tx * 4];
            float aa[4] = {a4.x, a4.y, a4.z, a4.w};
            float bb[4] = {b4.x, b4.y, b4.z, b4.w};
            #pragma unroll
            for (int i = 0; i < 4; i++)
                #pragma unroll
                for (int j = 0; j < 4; j++)
                    s[i][j] = fmaf(aa[i], bb[j], s[i][j]);
        }

        // mask (LOCAL = disallowed) + scale
        #pragma unroll
        for (int j = 0; j < 4; j++) {
            int kg = k0 + tx * 4 + j;
            int kr = kg / GG, kc = kg % GG;
            #pragma unroll
            for (int i = 0; i < 4; i++) {
                bool masked = (kg >= TT) ||
                              (abs(qr_[i] - kr) <= 4 && abs(qc_[i] - kc) <= 4);
                s[i][j] = masked ? -3.0e38f : s[i][j] * 0.125f;
            }
        }

        // online softmax update (row groups = 16 lanes within wave)
        float p_[4][4];
        #pragma unroll
        for (int i = 0; i < 4; i++) {
            float mx = fmaxf(fmaxf(s[i][0], s[i][1]), fmaxf(s[i][2], s[i][3]));
            mx = fmaxf(mx, __shfl_xor(mx, 1, 64));
            mx = fmaxf(mx, __shfl_xor(mx, 2, 64));
            mx = fmaxf(mx, __shfl_xor(mx, 4, 64));
            mx = fmaxf(mx, __shfl_xor(mx, 8, 64));
            float m_new = fmaxf(m_run[i], mx);
            float alpha = __expf(m_run[i] - m_new);
            float rs = 0.f;
            #pragma unroll
            for (int j = 0; j < 4; j++) {
                float pv = __expf(s[i][j] - m_new);
                p_[i][j] = pv;
                rs += pv;
            }
            rs += __shfl_xor(rs, 1, 64);
            rs += __shfl_xor(rs, 2, 64);
            rs += __shfl_xor(rs, 4, 64);
            rs += __shfl_xor(rs, 8, 64);
            l_run[i] = l_run[i] * alpha + rs;
            m_run[i] = m_new;
            #pragma unroll
            for (int j = 0; j < 4; j++) o_acc[i][j] *= alpha;
        }

        __syncthreads();   // done reading Ks as K
        // write P into Ks region as P[c][r]
        #pragma unroll
        for (int j = 0; j < 4; j++) {
            float4 pv = make_float4(p_[0][j], p_[1][j], p_[2][j], p_[3][j]);
            *(float4*)&Ks[tx * 4 + j][ty * 4] = pv;
        }
        __syncthreads();

        // O += P @ V
        #pragma unroll 8
        for (int c = 0; c < 64; c++) {
            float4 p4 = *(const float4*)&Ks[c][ty * 4];
            float4 v4 = *(const float4*)&Vs[c][tx * 4];
            float pp[4] = {p4.x, p4.y, p4.z, p4.w};
            float vv[4] = {v4.x, v4.y, v4.z, v4.w};
            #pragma unroll
            for (int i = 0; i < 4; i++)
                #pragma unroll
                for (int j = 0; j < 4; j++)
                    o_acc[i][j] = fmaf(pp[i], vv[j], o_acc[i][j]);
        }
    }

    #pragma unroll
    for (int i = 0; i < 4; i++) {
        if (qg_[i] < TT) {
            float inv = 1.0f / fmaxf(l_run[i], 1e-30f);
            float4 ov = make_float4(o_acc[i][0] * inv, o_acc[i][1] * inv,
                                    o_acc[i][2] * inv, o_acc[i][3] * inv);
            *(float4*)&O[(size_t)(b * TT + qg_[i]) * EE + hh * 64 + tx * 4] = ov;
        }
    }
}

// ---------------------------------------------------------------- head: logits -> patch flux
__global__ __launch_bounds__(256) void head_kernel(const float* __restrict__ Y,
                                                   const float* __restrict__ hw,
                                                   const float* __restrict__ hb,
                                                   const float* __restrict__ mean_,
                                                   const float* __restrict__ std_,
                                                   float* __restrict__ out) {
    __shared__ float sb[4];
    int row = blockIdx.x;
    int tid = threadIdx.x;
    const float* y = Y + (size_t)row * EE;
    float v = y[tid] * hw[tid] + y[tid + 256] * hw[tid + 256] + y[tid + 512] * hw[tid + 512];
    v = block_reduce_sum256(v, sb);
    if (tid == 0) {
        float logit = v + hb[0];
        float z = logit * std_[0] + mean_[0];
        float f = expf(z * 2.302585092994046f) - 1e-8f;   // 10^z
        f = fminf(fmaxf(f, 1e-15f), 1.0f);
        out[4 + row] = f;
    }
}

// ---------------------------------------------------------------- global flux = max(sum_t patch_flux, 1e-15)
__global__ __launch_bounds__(256) void flux_sum_kernel(float* __restrict__ out) {
    __shared__ float sb[4];
    int b = blockIdx.x;
    int tid = threadIdx.x;
    const float* pf = out + 4 + (size_t)b * TT;
    float v = pf[tid] + pf[tid + 256] + pf[tid + 512];
    if (tid < TT - 768) v += pf[tid + 768];
    v = block_reduce_sum256(v, sb);
    if (tid == 0) out[b] = fmaxf(v, 1e-15f);
}

// ---------------------------------------------------------------- host
extern "C" void kernel_launch(void* const* d_in, const int* in_sizes, int n_in,
                              void* d_out, int out_size, void* d_ws, size_t ws_size,
                              hipStream_t stream) {
    const float* x        = (const float*)d_in[0];
    const float* sxr_mean = (const float*)d_in[1];
    const float* sxr_std  = (const float*)d_in[2];
    const float* input_w  = (const float*)d_in[3];
    const float* input_b  = (const float*)d_in[4];
    const float* pos_emb  = (const float*)d_in[5];
    const float* ln1_w    = (const float*)d_in[6];
    const float* ln1_b    = (const float*)d_in[7];
    const float* in_w     = (const float*)d_in[8];
    const float* in_b     = (const float*)d_in[9];
    const float* out_w    = (const float*)d_in[10];
    const float* out_b    = (const float*)d_in[11];
    const float* ln2_w    = (const float*)d_in[12];
    const float* ln2_b    = (const float*)d_in[13];
    const float* w1       = (const float*)d_in[14];
    const float* b1       = (const float*)d_in[15];
    const float* w2       = (const float*)d_in[16];
    const float* b2       = (const float*)d_in[17];
    const float* head_ln_w = (const float*)d_in[18];
    const float* head_ln_b = (const float*)d_in[19];
    const float* head_w   = (const float*)d_in[20];
    const float* head_b   = (const float*)d_in[21];
    float* out = (float*)d_out;

    const size_t NROW = (size_t)BB * TT;          // 3136
    float* ws  = (float*)d_ws;
    float* h   = ws;                               // [3136,768]
    float* y   = h   + NROW * EE;                  // [3136,768]
    float* qkv = y   + NROW * EE;                  // [3136,2304]
    float* o   = qkv + NROW * 3 * EE;              // [3136,768]
    float* mlp = o   + NROW * EE;                  // [3136,3072] (also patches)

    const int tot = BB * TT * EE;

    patchify_kernel<<<(tot + 255) / 256, 256, 0, stream>>>(x, mlp);
    gemm_kernel<<<dim3(EE / 64, NROW / 64), 256, 0, stream>>>(
        mlp, input_w, input_b, nullptr, h, (int)NROW, EE, EE, 0);
    addpos_kernel<<<(tot + 255) / 256, 256, 0, stream>>>(h, pos_emb);

    for (int l = 0; l < NLAYER; l++) {
        ln_kernel<<<(int)NROW, 256, 0, stream>>>(h, ln1_w + l * EE, ln1_b + l * EE, y);
        gemm_kernel<<<dim3(3 * EE / 64, NROW / 64), 256, 0, stream>>>(
            y, in_w + (size_t)l * 3 * EE * EE, in_b + (size_t)l * 3 * EE,
            nullptr, qkv, (int)NROW, 3 * EE, EE, 0);
        attn_kernel<<<dim3((TT + 63) / 64, BB * NHEAD), 256, 0, stream>>>(qkv, o);
        gemm_kernel<<<dim3(EE / 64, NROW / 64), 256, 0, stream>>>(
            o, out_w + (size_t)l * EE * EE, out_b + (size_t)l * EE,
            h, h, (int)NROW, EE, EE, 0);
        ln_kernel<<<(int)NROW, 256, 0, stream>>>(h, ln2_w + l * EE, ln2_b + l * EE, y);
        gemm_kernel<<<dim3(HDIM / 64, NROW / 64), 256, 0, stream>>>(
            y, w1 + (size_t)l * HDIM * EE, b1 + (size_t)l * HDIM,
            nullptr, mlp, (int)NROW, HDIM, EE, 1);
        gemm_kernel<<<dim3(EE / 64, NROW / 64), 256, 0, stream>>>(
            mlp, w2 + (size_t)l * EE * HDIM, b2 + (size_t)l * EE,
            h, h, (int)NROW, EE, HDIM, 0);
    }

    ln_kernel<<<(int)NROW, 256, 0, stream>>>(h, head_ln_w, head_ln_b, y);
    head_kernel<<<(int)NROW, 256, 0, stream>>>(y, head_w, head_b, sxr_mean, sxr_std, out);
    flux_sum_kernel<<<BB, 256, 0, stream>>>(out);
}

// Round 2
// 2667.613 us; speedup vs baseline: 2.0008x; 2.0008x over previous
//
#include <hip/hip_runtime.h>
#include <math.h>

#define BB 4
#define TT 784
#define GG 28
#define EE 768
#define HDIM 3072
#define NHEAD 12
#define NLAYER 6

typedef short bfrag __attribute__((ext_vector_type(8)));   // 8 bf16 = 4 VGPRs
typedef float ffrag __attribute__((ext_vector_type(4)));   // 4 fp32 acc

__device__ __forceinline__ unsigned short f2b(float f) {
    union { float f; unsigned u; } v; v.f = f;
    unsigned r = v.u + 0x7FFF + ((v.u >> 16) & 1);         // RNE
    return (unsigned short)(r >> 16);
}

#define GLOAD_LDS16(g, l)                                                          \
    __builtin_amdgcn_global_load_lds(                                              \
        (const __attribute__((address_space(1))) void*)(g),                        \
        (__attribute__((address_space(3))) void*)(l), 16, 0, 0)

// ---------------------------------------------------------------- reductions
__device__ __forceinline__ float block_reduce_sum256(float v, volatile float* sb) {
    #pragma unroll
    for (int m = 1; m < 64; m <<= 1) v += __shfl_xor(v, m, 64);
    int wave = threadIdx.x >> 6;
    if ((threadIdx.x & 63) == 0) sb[wave] = v;
    __syncthreads();
    return sb[0] + sb[1] + sb[2] + sb[3];
}

// ---------------------------------------------------------------- fp32 -> bf16 cast (n divisible by 4)
__global__ __launch_bounds__(256) void cast_kernel(const float* __restrict__ s,
                                                   unsigned short* __restrict__ d, int n4) {
    int i = blockIdx.x * 256 + threadIdx.x;
    if (i >= n4) return;
    float4 v = ((const float4*)s)[i];
    ushort4 o;
    o.x = f2b(v.x); o.y = f2b(v.y); o.z = f2b(v.z); o.w = f2b(v.w);
    ((ushort4*)d)[i] = o;
}

// ---------------------------------------------------------------- patchify -> bf16
__global__ __launch_bounds__(256) void patchify_kernel(const float* __restrict__ x,
                                                       unsigned short* __restrict__ P) {
    int idx = blockIdx.x * blockDim.x + threadIdx.x;
    const int total = BB * TT * EE;
    if (idx >= total) return;
    int k = idx % EE;
    int t = (idx / EE) % TT;
    int b = idx / (EE * TT);
    int c = k >> 8;
    int rem = k & 255;
    int p1 = rem >> 4;
    int p2 = rem & 15;
    int g1 = t / GG, g2 = t % GG;
    int hh = g1 * 16 + p1, ww = g2 * 16 + p2;
    P[idx] = f2b(x[((b * 448 + hh) * 448 + ww) * 3 + c]);
}

// ---------------------------------------------------------------- pos add (fp32 h)
__global__ __launch_bounds__(256) void addpos_kernel(float* __restrict__ h,
                                                     const float* __restrict__ pos) {
    int idx = blockIdx.x * blockDim.x + threadIdx.x;
    const int total = BB * TT * EE;
    if (idx >= total) return;
    int e = idx % EE;
    int t = (idx / EE) % TT;
    h[idx] += pos[t * EE + e];
}

// ---------------------------------------------------------------- layernorm: fp32 in, bf16 out (+opt fp32)
__global__ __launch_bounds__(256) void ln_kernel(const float* __restrict__ X,
                                                 const float* __restrict__ g,
                                                 const float* __restrict__ bt,
                                                 unsigned short* __restrict__ Yb,
                                                 float* Yf) {
    __shared__ float sb1[4];
    __shared__ float sb2[4];
    int row = blockIdx.x;
    int tid = threadIdx.x;
    const float* x = X + (size_t)row * EE;
    float v0 = x[tid], v1 = x[tid + 256], v2 = x[tid + 512];
    float s = block_reduce_sum256(v0 + v1 + v2, sb1);
    float mean = s * (1.0f / 768.0f);
    float d0 = v0 - mean, d1 = v1 - mean, d2 = v2 - mean;
    __syncthreads();
    float ss = block_reduce_sum256(d0 * d0 + d1 * d1 + d2 * d2, sb2);
    float rstd = rsqrtf(ss * (1.0f / 768.0f) + 1e-5f);
    float y0 = d0 * rstd * g[tid]       + bt[tid];
    float y1 = d1 * rstd * g[tid + 256] + bt[tid + 256];
    float y2 = d2 * rstd * g[tid + 512] + bt[tid + 512];
    unsigned short* yb = Yb + (size_t)row * EE;
    yb[tid] = f2b(y0); yb[tid + 256] = f2b(y1); yb[tid + 512] = f2b(y2);
    if (Yf) {
        float* yf = Yf + (size_t)row * EE;
        yf[tid] = y0; yf[tid + 256] = y1; yf[tid + 512] = y2;
    }
}

// ---------------------------------------------------------------- bf16 MFMA GEMM: C = A @ W^T + bias (+R)(+gelu)
// A: [M,K] bf16 row-major; W: [N,K] bf16 row-major; bias fp32 [N].
// R fp32 [M,N] or null (residual; may alias C). C fp32 or null; Cb bf16 or null.
// Tile 128x128, BK=32, 256 threads (4 waves, each 64x64 via 4x4 mfma_16x16x32).
__global__ __launch_bounds__(256) void gemm_bf16(const unsigned short* __restrict__ A,
                                                 const unsigned short* __restrict__ W,
                                                 const float* __restrict__ bias,
                                                 const float* R, float* C,
                                                 unsigned short* Cb,
                                                 int M, int N, int K, int act) {
    __shared__ unsigned short As[128 * 32];  // row-major [r][k], 64B rows, NO padding
    __shared__ unsigned short Ws[128 * 32];
    int tid = threadIdx.x;
    int wave = tid >> 6, lane = tid & 63;
    int m0 = blockIdx.y << 7, n0 = blockIdx.x << 7;
    int mh = (wave & 1) << 6, nh = (wave >> 1) << 6;

    int cl = lane & 15, qd = lane >> 4;      // frag row/col + quad
    int sr = lane >> 2;                      // staging row within 16-row group
    int sc = (lane & 3) << 3;                // staging k-offset (elements)

    // staging pointers (2 A-instrs + 2 W-instrs per wave; 16 rows each)
    const unsigned short* Ap[2];
    const unsigned short* Wp[2];
    unsigned short* lA[2];
    unsigned short* lW[2];
    #pragma unroll
    for (int i = 0; i < 2; i++) {
        int ar = m0 + (wave << 5) + (i << 4) + sr;
        if (ar > M - 1) ar = M - 1;
        Ap[i] = A + (size_t)ar * K + sc;
        int wr = n0 + (wave << 5) + (i << 4) + sr;
        Wp[i] = W + (size_t)wr * K + sc;
        lA[i] = &As[((wave << 5) + (i << 4)) << 5];
        lW[i] = &Ws[((wave << 5) + (i << 4)) << 5];
    }

    ffrag acc[4][4] = {};

    for (int k0 = 0; k0 < K; k0 += 32) {
        __syncthreads();
        GLOAD_LDS16(Ap[0] + k0, lA[0]);
        GLOAD_LDS16(Ap[1] + k0, lA[1]);
        GLOAD_LDS16(Wp[0] + k0, lW[0]);
        GLOAD_LDS16(Wp[1] + k0, lW[1]);
        __syncthreads();

        bfrag af[4], bfr[4];
        #pragma unroll
        for (int i = 0; i < 4; i++)
            af[i] = *(const bfrag*)&As[(((mh + (i << 4) + cl)) << 5) + (qd << 3)];
        #pragma unroll
        for (int j = 0; j < 4; j++)
            bfr[j] = *(const bfrag*)&Ws[(((nh + (j << 4) + cl)) << 5) + (qd << 3)];
        #pragma unroll
        for (int i = 0; i < 4; i++)
            #pragma unroll
            for (int j = 0; j < 4; j++)
                acc[i][j] = __builtin_amdgcn_mfma_f32_16x16x32_bf16(af[i], bfr[j], acc[i][j], 0, 0, 0);
    }

    // epilogue: D[row][col], col = lane&15, row = quad*4 + reg
    #pragma unroll
    for (int j = 0; j < 4; j++) {
        int col = n0 + nh + (j << 4) + cl;
        float bv = bias[col];
        #pragma unroll
        for (int i = 0; i < 4; i++) {
            int row0 = m0 + mh + (i << 4) + (qd << 2);
            #pragma unroll
            for (int r = 0; r < 4; r++) {
                int row = row0 + r;
                if (row < M) {
                    float v = acc[i][j][r] + bv;
                    if (R) v += R[(size_t)row * N + col];
                    if (act) v = 0.5f * v * (1.0f + erff(v * 0.70710678118654752f));
                    if (C)  C[(size_t)row * N + col] = v;
                    if (Cb) Cb[(size_t)row * N + col] = f2b(v);
                }
            }
        }
    }
}

// ---------------------------------------------------------------- flash attention, local-mask (masked OUT), bf16 O
__global__ __launch_bounds__(256) void attn_kernel(const float* __restrict__ qkv,
                                                   unsigned short* __restrict__ O) {
    __shared__ float Qs[64][68];
    __shared__ float Ks[64][68];
    __shared__ float Vs[64][68];
    int tid = threadIdx.x;
    int tx = tid & 15, ty = tid >> 4;
    int bh = blockIdx.y;
    int b = bh / NHEAD, hh = bh % NHEAD;
    int q0 = blockIdx.x * 64;

    #pragma unroll
    for (int p = 0; p < 4; p++) {
        int f4 = tid + p * 256;
        int r = f4 >> 4;
        int d4 = (f4 & 15) << 2;
        int qg = q0 + r;
        float4 qv = make_float4(0.f, 0.f, 0.f, 0.f);
        if (qg < TT)
            qv = *(const float4*)&qkv[(size_t)(b * TT + qg) * 2304 + hh * 64 + d4];
        Qs[d4 + 0][r] = qv.x; Qs[d4 + 1][r] = qv.y;
        Qs[d4 + 2][r] = qv.z; Qs[d4 + 3][r] = qv.w;
    }

    float o_acc[4][4] = {};
    float m_run[4], l_run[4];
    int qr_[4], qc_[4], qg_[4];
    #pragma unroll
    for (int i = 0; i < 4; i++) {
        m_run[i] = -1e30f; l_run[i] = 0.0f;
        qg_[i] = q0 + ty * 4 + i;
        qr_[i] = qg_[i] / GG;
        qc_[i] = qg_[i] % GG;
    }

    for (int k0 = 0; k0 < TT; k0 += 64) {
        __syncthreads();
        #pragma unroll
        for (int p = 0; p < 4; p++) {
            int f4 = tid + p * 256;
            int r = f4 >> 4;
            int d4 = (f4 & 15) << 2;
            int kg = k0 + r;
            float4 kv = make_float4(0.f, 0.f, 0.f, 0.f);
            float4 vv = make_float4(0.f, 0.f, 0.f, 0.f);
            if (kg < TT) {
                size_t base = (size_t)(b * TT + kg) * 2304 + hh * 64 + d4;
                kv = *(const float4*)&qkv[base + 768];
                vv = *(const float4*)&qkv[base + 1536];
            }
            Ks[d4 + 0][r] = kv.x; Ks[d4 + 1][r] = kv.y;
            Ks[d4 + 2][r] = kv.z; Ks[d4 + 3][r] = kv.w;
            *(float4*)&Vs[r][d4] = vv;
        }
        __syncthreads();

        float s[4][4] = {};
        #pragma unroll 8
        for (int d = 0; d < 64; d++) {
            float4 a4 = *(const float4*)&Qs[d][ty * 4];
            float4 b4 = *(const float4*)&Ks[d][tx * 4];
            float aa[4] = {a4.x, a4.y, a4.z, a4.w};
            float bb[4] = {b4.x, b4.y, b4.z, b4.w};
            #pragma unroll
            for (int i = 0; i < 4; i++)
                #pragma unroll
                for (int j = 0; j < 4; j++)
                    s[i][j] = fmaf(aa[i], bb[j], s[i][j]);
        }

        #pragma unroll
        for (int j = 0; j < 4; j++) {
            int kg = k0 + tx * 4 + j;
            int kr = kg / GG, kc = kg % GG;
            #pragma unroll
            for (int i = 0; i < 4; i++) {
                bool masked = (kg >= TT) ||
                              (abs(qr_[i] - kr) <= 4 && abs(qc_[i] - kc) <= 4);
                s[i][j] = masked ? -3.0e38f : s[i][j] * 0.125f;
            }
        }

        float p_[4][4];
        #pragma unroll
        for (int i = 0; i < 4; i++) {
            float mx = fmaxf(fmaxf(s[i][0], s[i][1]), fmaxf(s[i][2], s[i][3]));
            mx = fmaxf(mx, __shfl_xor(mx, 1, 64));
            mx = fmaxf(mx, __shfl_xor(mx, 2, 64));
            mx = fmaxf(mx, __shfl_xor(mx, 4, 64));
            mx = fmaxf(mx, __shfl_xor(mx, 8, 64));
            float m_new = fmaxf(m_run[i], mx);
            float alpha = __expf(m_run[i] - m_new);
            float rs = 0.f;
            #pragma unroll
            for (int j = 0; j < 4; j++) {
                float pv = __expf(s[i][j] - m_new);
                p_[i][j] = pv;
                rs += pv;
            }
            rs += __shfl_xor(rs, 1, 64);
            rs += __shfl_xor(rs, 2, 64);
            rs += __shfl_xor(rs, 4, 64);
            rs += __shfl_xor(rs, 8, 64);
            l_run[i] = l_run[i] * alpha + rs;
            m_run[i] = m_new;
            #pragma unroll
            for (int j = 0; j < 4; j++) o_acc[i][j] *= alpha;
        }

        __syncthreads();
        #pragma unroll
        for (int j = 0; j < 4; j++) {
            float4 pv = make_float4(p_[0][j], p_[1][j], p_[2][j], p_[3][j]);
            *(float4*)&Ks[tx * 4 + j][ty * 4] = pv;
        }
        __syncthreads();

        #pragma unroll 8
        for (int c = 0; c < 64; c++) {
            float4 p4 = *(const float4*)&Ks[c][ty * 4];
            float4 v4 = *(const float4*)&Vs[c][tx * 4];
            float pp[4] = {p4.x, p4.y, p4.z, p4.w};
            float vv[4] = {v4.x, v4.y, v4.z, v4.w};
            #pragma unroll
            for (int i = 0; i < 4; i++)
                #pragma unroll
                for (int j = 0; j < 4; j++)
                    o_acc[i][j] = fmaf(pp[i], vv[j], o_acc[i][j]);
        }
    }

    #pragma unroll
    for (int i = 0; i < 4; i++) {
        if (qg_[i] < TT) {
            float inv = 1.0f / fmaxf(l_run[i], 1e-30f);
            ushort4 ov;
            ov.x = f2b(o_acc[i][0] * inv);
            ov.y = f2b(o_acc[i][1] * inv);
            ov.z = f2b(o_acc[i][2] * inv);
            ov.w = f2b(o_acc[i][3] * inv);
            *(ushort4*)&O[(size_t)(b * TT + qg_[i]) * EE + hh * 64 + tx * 4] = ov;
        }
    }
}

// ---------------------------------------------------------------- head: logits -> patch flux
__global__ __launch_bounds__(256) void head_kernel(const float* __restrict__ Y,
                                                   const float* __restrict__ hw,
                                                   const float* __restrict__ hb,
                                                   const float* __restrict__ mean_,
                                                   const float* __restrict__ std_,
                                                   float* __restrict__ out) {
    __shared__ float sb[4];
    int row = blockIdx.x;
    int tid = threadIdx.x;
    const float* y = Y + (size_t)row * EE;
    float v = y[tid] * hw[tid] + y[tid + 256] * hw[tid + 256] + y[tid + 512] * hw[tid + 512];
    v = block_reduce_sum256(v, sb);
    if (tid == 0) {
        float logit = v + hb[0];
        float z = logit * std_[0] + mean_[0];
        float f = expf(z * 2.302585092994046f) - 1e-8f;
        f = fminf(fmaxf(f, 1e-15f), 1.0f);
        out[4 + row] = f;
    }
}

__global__ __launch_bounds__(256) void flux_sum_kernel(float* __restrict__ out) {
    __shared__ float sb[4];
    int b = blockIdx.x;
    int tid = threadIdx.x;
    const float* pf = out + 4 + (size_t)b * TT;
    float v = pf[tid] + pf[tid + 256] + pf[tid + 512];
    if (tid < TT - 768) v += pf[tid + 768];
    v = block_reduce_sum256(v, sb);
    if (tid == 0) out[b] = fmaxf(v, 1e-15f);
}

// ---------------------------------------------------------------- host
extern "C" void kernel_launch(void* const* d_in, const int* in_sizes, int n_in,
                              void* d_out, int out_size, void* d_ws, size_t ws_size,
                              hipStream_t stream) {
    const float* x        = (const float*)d_in[0];
    const float* sxr_mean = (const float*)d_in[1];
    const float* sxr_std  = (const float*)d_in[2];
    const float* input_w  = (const float*)d_in[3];
    const float* input_b  = (const float*)d_in[4];
    const float* pos_emb  = (const float*)d_in[5];
    const float* ln1_w    = (const float*)d_in[6];
    const float* ln1_b    = (const float*)d_in[7];
    const float* in_w     = (const float*)d_in[8];
    const float* in_b     = (const float*)d_in[9];
    const float* out_w    = (const float*)d_in[10];
    const float* out_b    = (const float*)d_in[11];
    const float* ln2_w    = (const float*)d_in[12];
    const float* ln2_b    = (const float*)d_in[13];
    const float* w1       = (const float*)d_in[14];
    const float* b1       = (const float*)d_in[15];
    const float* w2       = (const float*)d_in[16];
    const float* b2       = (const float*)d_in[17];
    const float* head_ln_w = (const float*)d_in[18];
    const float* head_ln_b = (const float*)d_in[19];
    const float* head_w   = (const float*)d_in[20];
    const float* head_b   = (const float*)d_in[21];
    float* out = (float*)d_out;

    const size_t NROW = (size_t)BB * TT;               // 3136
    const size_t NE   = NROW * EE;                     // 2,408,448

    float* h      = (float*)d_ws;                      // [3136,768] f32
    float* qkv32  = h + NE;                            // [3136,2304] f32 (reused as y32 at head)
    unsigned short* y_b   = (unsigned short*)(qkv32 + NROW * 3 * EE);
    unsigned short* o_b   = y_b + NE;
    unsigned short* mlp_b = o_b + NE;                  // [3136,3072] bf16 (also bf16 patches)
    unsigned short* wq_b  = mlp_b + NROW * HDIM;       // [2304,768]
    unsigned short* wo_b  = wq_b + (size_t)3 * EE * EE;// [768,768]
    unsigned short* w1_b  = wo_b + (size_t)EE * EE;    // [3072,768]
    unsigned short* w2_b  = w1_b + (size_t)HDIM * EE;  // [768,3072]
    float* y32 = qkv32;

    const int tot = BB * TT * EE;
    const int GY = (int)((NROW + 127) / 128);          // 25

    // patch embed (input_w cast into wo_b region, free at this point)
    patchify_kernel<<<(tot + 255) / 256, 256, 0, stream>>>(x, mlp_b);
    cast_kernel<<<(EE * EE / 4 + 255) / 256, 256, 0, stream>>>(input_w, wo_b, EE * EE / 4);
    gemm_bf16<<<dim3(EE / 128, GY), 256, 0, stream>>>(
        mlp_b, wo_b, input_b, nullptr, h, nullptr, (int)NROW, EE, EE, 0);
    addpos_kernel<<<(tot + 255) / 256, 256, 0, stream>>>(h, pos_emb);

    for (int l = 0; l < NLAYER; l++) {
        cast_kernel<<<(3 * EE * EE / 4 + 255) / 256, 256, 0, stream>>>(
            in_w + (size_t)l * 3 * EE * EE, wq_b, 3 * EE * EE / 4);
        cast_kernel<<<(EE * EE / 4 + 255) / 256, 256, 0, stream>>>(
            out_w + (size_t)l * EE * EE, wo_b, EE * EE / 4);
        cast_kernel<<<(HDIM * EE / 4 + 255) / 256, 256, 0, stream>>>(
            w1 + (size_t)l * HDIM * EE, w1_b, HDIM * EE / 4);
        cast_kernel<<<(EE * HDIM / 4 + 255) / 256, 256, 0, stream>>>(
            w2 + (size_t)l * EE * HDIM, w2_b, EE * HDIM / 4);

        ln_kernel<<<(int)NROW, 256, 0, stream>>>(h, ln1_w + l * EE, ln1_b + l * EE, y_b, nullptr);
        gemm_bf16<<<dim3(3 * EE / 128, GY), 256, 0, stream>>>(
            y_b, wq_b, in_b + (size_t)l * 3 * EE, nullptr, qkv32, nullptr,
            (int)NROW, 3 * EE, EE, 0);
        attn_kernel<<<dim3((TT + 63) / 64, BB * NHEAD), 256, 0, stream>>>(qkv32, o_b);
        gemm_bf16<<<dim3(EE / 128, GY), 256, 0, stream>>>(
            o_b, wo_b, out_b + (size_t)l * EE, h, h, nullptr,
            (int)NROW, EE, EE, 0);
        ln_kernel<<<(int)NROW, 256, 0, stream>>>(h, ln2_w + l * EE, ln2_b + l * EE, y_b, nullptr);
        gemm_bf16<<<dim3(HDIM / 128, GY), 256, 0, stream>>>(
            y_b, w1_b, b1 + (size_t)l * HDIM, nullptr, nullptr, mlp_b,
            (int)NROW, HDIM, EE, 1);
        gemm_bf16<<<dim3(EE / 128, GY), 256, 0, stream>>>(
            mlp_b, w2_b, b2 + (size_t)l * EE, h, h, nullptr,
            (int)NROW, EE, HDIM, 0);
    }

    ln_kernel<<<(int)NROW, 256, 0, stream>>>(h, head_ln_w, head_ln_b, y_b, y32);
    head_kernel<<<(int)NROW, 256, 0, stream>>>(y32, head_w, head_b, sxr_mean, sxr_std, out);
    flux_sum_kernel<<<BB, 256, 0, stream>>>(out);
}

// Round 3
// 2072.852 us; speedup vs baseline: 2.5749x; 1.2869x over previous
//
#include <hip/hip_runtime.h>
#include <math.h>

#define BB 4
#define TT 784
#define GG 28
#define EE 768
#define HDIM 3072
#define NHEAD 12
#define NLAYER 6

typedef short bfrag __attribute__((ext_vector_type(8)));   // 8 bf16 = 4 VGPRs
typedef float ffrag __attribute__((ext_vector_type(4)));   // 4 fp32 acc

__device__ __forceinline__ unsigned short f2b(float f) {
    union { float f; unsigned u; } v; v.f = f;
    unsigned r = v.u + 0x7FFF + ((v.u >> 16) & 1);         // RNE
    return (unsigned short)(r >> 16);
}

#define GLOAD_LDS16(g, l)                                                          \
    __builtin_amdgcn_global_load_lds(                                              \
        (const __attribute__((address_space(1))) void*)(g),                        \
        (__attribute__((address_space(3))) void*)(l), 16, 0, 0)

// ---------------------------------------------------------------- reductions
__device__ __forceinline__ float block_reduce_sum256(float v, volatile float* sb) {
    #pragma unroll
    for (int m = 1; m < 64; m <<= 1) v += __shfl_xor(v, m, 64);
    int wave = threadIdx.x >> 6;
    if ((threadIdx.x & 63) == 0) sb[wave] = v;
    __syncthreads();
    return sb[0] + sb[1] + sb[2] + sb[3];
}

// ---------------------------------------------------------------- fp32 -> bf16 cast
__global__ __launch_bounds__(256) void cast_kernel(const float* __restrict__ s,
                                                   unsigned short* __restrict__ d, int n4) {
    int i = blockIdx.x * 256 + threadIdx.x;
    if (i >= n4) return;
    float4 v = ((const float4*)s)[i];
    ushort4 o;
    o.x = f2b(v.x); o.y = f2b(v.y); o.z = f2b(v.z); o.w = f2b(v.w);
    ((ushort4*)d)[i] = o;
}

// ---------------------------------------------------------------- patchify -> bf16
__global__ __launch_bounds__(256) void patchify_kernel(const float* __restrict__ x,
                                                       unsigned short* __restrict__ P) {
    int idx = blockIdx.x * blockDim.x + threadIdx.x;
    const int total = BB * TT * EE;
    if (idx >= total) return;
    int k = idx % EE;
    int t = (idx / EE) % TT;
    int b = idx / (EE * TT);
    int c = k >> 8;
    int rem = k & 255;
    int p1 = rem >> 4;
    int p2 = rem & 15;
    int g1 = t / GG, g2 = t % GG;
    int hh = g1 * 16 + p1, ww = g2 * 16 + p2;
    P[idx] = f2b(x[((b * 448 + hh) * 448 + ww) * 3 + c]);
}

// ---------------------------------------------------------------- pos add (fp32 h)
__global__ __launch_bounds__(256) void addpos_kernel(float* __restrict__ h,
                                                     const float* __restrict__ pos) {
    int idx = blockIdx.x * blockDim.x + threadIdx.x;
    const int total = BB * TT * EE;
    if (idx >= total) return;
    int e = idx % EE;
    int t = (idx / EE) % TT;
    h[idx] += pos[t * EE + e];
}

// ---------------------------------------------------------------- layernorm: fp32 in, bf16 out (+opt fp32)
__global__ __launch_bounds__(256) void ln_kernel(const float* __restrict__ X,
                                                 const float* __restrict__ g,
                                                 const float* __restrict__ bt,
                                                 unsigned short* __restrict__ Yb,
                                                 float* Yf) {
    __shared__ float sb1[4];
    __shared__ float sb2[4];
    int row = blockIdx.x;
    int tid = threadIdx.x;
    const float* x = X + (size_t)row * EE;
    float v0 = x[tid], v1 = x[tid + 256], v2 = x[tid + 512];
    float s = block_reduce_sum256(v0 + v1 + v2, sb1);
    float mean = s * (1.0f / 768.0f);
    float d0 = v0 - mean, d1 = v1 - mean, d2 = v2 - mean;
    __syncthreads();
    float ss = block_reduce_sum256(d0 * d0 + d1 * d1 + d2 * d2, sb2);
    float rstd = rsqrtf(ss * (1.0f / 768.0f) + 1e-5f);
    float y0 = d0 * rstd * g[tid]       + bt[tid];
    float y1 = d1 * rstd * g[tid + 256] + bt[tid + 256];
    float y2 = d2 * rstd * g[tid + 512] + bt[tid + 512];
    unsigned short* yb = Yb + (size_t)row * EE;
    yb[tid] = f2b(y0); yb[tid + 256] = f2b(y1); yb[tid + 512] = f2b(y2);
    if (Yf) {
        float* yf = Yf + (size_t)row * EE;
        yf[tid] = y0; yf[tid + 256] = y1; yf[tid + 512] = y2;
    }
}

// ---------------------------------------------------------------- bf16 MFMA GEMM (m97-style)
__global__ __launch_bounds__(256) void gemm_bf16(const unsigned short* __restrict__ A,
                                                 const unsigned short* __restrict__ W,
                                                 const float* __restrict__ bias,
                                                 const float* R, float* C,
                                                 unsigned short* Cb,
                                                 int M, int N, int K, int act) {
    __shared__ unsigned short As[128 * 32];
    __shared__ unsigned short Ws[128 * 32];
    int tid = threadIdx.x;
    int wave = tid >> 6, lane = tid & 63;
    int m0 = blockIdx.y << 7, n0 = blockIdx.x << 7;
    int mh = (wave & 1) << 6, nh = (wave >> 1) << 6;

    int cl = lane & 15, qd = lane >> 4;
    int sr = lane >> 2;
    int sc = (lane & 3) << 3;

    const unsigned short* Ap[2];
    const unsigned short* Wp[2];
    unsigned short* lA[2];
    unsigned short* lW[2];
    #pragma unroll
    for (int i = 0; i < 2; i++) {
        int ar = m0 + (wave << 5) + (i << 4) + sr;
        if (ar > M - 1) ar = M - 1;
        Ap[i] = A + (size_t)ar * K + sc;
        int wr = n0 + (wave << 5) + (i << 4) + sr;
        Wp[i] = W + (size_t)wr * K + sc;
        lA[i] = &As[((wave << 5) + (i << 4)) << 5];
        lW[i] = &Ws[((wave << 5) + (i << 4)) << 5];
    }

    ffrag acc[4][4] = {};

    for (int k0 = 0; k0 < K; k0 += 32) {
        __syncthreads();
        GLOAD_LDS16(Ap[0] + k0, lA[0]);
        GLOAD_LDS16(Ap[1] + k0, lA[1]);
        GLOAD_LDS16(Wp[0] + k0, lW[0]);
        GLOAD_LDS16(Wp[1] + k0, lW[1]);
        __syncthreads();

        bfrag af[4], bfr[4];
        #pragma unroll
        for (int i = 0; i < 4; i++)
            af[i] = *(const bfrag*)&As[(((mh + (i << 4) + cl)) << 5) + (qd << 3)];
        #pragma unroll
        for (int j = 0; j < 4; j++)
            bfr[j] = *(const bfrag*)&Ws[(((nh + (j << 4) + cl)) << 5) + (qd << 3)];
        #pragma unroll
        for (int i = 0; i < 4; i++)
            #pragma unroll
            for (int j = 0; j < 4; j++)
                acc[i][j] = __builtin_amdgcn_mfma_f32_16x16x32_bf16(af[i], bfr[j], acc[i][j], 0, 0, 0);
    }

    #pragma unroll
    for (int j = 0; j < 4; j++) {
        int col = n0 + nh + (j << 4) + cl;
        float bv = bias[col];
        #pragma unroll
        for (int i = 0; i < 4; i++) {
            int row0 = m0 + mh + (i << 4) + (qd << 2);
            #pragma unroll
            for (int r = 0; r < 4; r++) {
                int row = row0 + r;
                if (row < M) {
                    float v = acc[i][j][r] + bv;
                    if (R) v += R[(size_t)row * N + col];
                    if (act) v = 0.5f * v * (1.0f + erff(v * 0.70710678118654752f));
                    if (C)  C[(size_t)row * N + col] = v;
                    if (Cb) Cb[(size_t)row * N + col] = f2b(v);
                }
            }
        }
    }
}

// ---------------------------------------------------------------- MFMA flash attention, local-mask (masked OUT)
// qkv bf16 [B*T, 3E]; O bf16 [B*T, E]. grid (13 qtiles, B*NH), block 256 (4 waves x 16 q-rows).
#define APAD 72
__global__ __launch_bounds__(256) void attn_kernel(const unsigned short* __restrict__ qkv,
                                                   unsigned short* __restrict__ O) {
    __shared__ unsigned short Ks[64 * APAD];   // [k'][d] row-major, pad 72
    __shared__ unsigned short Vt[64 * APAD];   // [d][k'] d-major, pad 72
    __shared__ unsigned short Pb[64 * APAD];   // [q_local][k'], wave-private rows
    int tid = threadIdx.x;
    int wave = tid >> 6, lane = tid & 63;
    int cl = lane & 15, qd = lane >> 4;
    int bh = blockIdx.y;
    int b = bh / NHEAD, hh = bh % NHEAD;
    int q0 = blockIdx.x * 64;

    // Q fragments (A-layout: m = cl, k = qd*8+j), held in registers
    int qrow = q0 + wave * 16 + cl;
    if (qrow > TT - 1) qrow = TT - 1;
    const unsigned short* qbase = qkv + (size_t)(b * TT + qrow) * 2304 + hh * 64;
    bfrag qf0 = *(const bfrag*)(qbase + (qd << 3));
    bfrag qf1 = *(const bfrag*)(qbase + 32 + (qd << 3));

    ffrag o_acc[4] = {};
    float m_run[4], l_run[4];
    int qg_[4], qr_[4], qc_[4];
    #pragma unroll
    for (int r = 0; r < 4; r++) {
        qg_[r] = q0 + wave * 16 + (qd << 2) + r;
        qr_[r] = qg_[r] / GG;
        qc_[r] = qg_[r] % GG;
        m_run[r] = -1e30f; l_run[r] = 0.0f;
    }

    int srow = tid >> 3;            // 0..31
    int sd = (tid & 7) << 3;        // 0..56

    for (int k0 = 0; k0 < 832; k0 += 64) {
        __syncthreads();            // protect Ks/Vt (and prior PV reads)
        #pragma unroll
        for (int it = 0; it < 2; it++) {
            int row = it * 32 + srow;
            int kg = k0 + row;
            int kgc = kg > TT - 1 ? TT - 1 : kg;
            const unsigned short* kb = qkv + (size_t)(b * TT + kgc) * 2304 + 768 + hh * 64 + sd;
            bfrag kv = *(const bfrag*)kb;
            *(bfrag*)&Ks[row * APAD + sd] = kv;
            bfrag vv = *(const bfrag*)(kb + 768);
            #pragma unroll
            for (int j = 0; j < 8; j++)
                Vt[(sd + j) * APAD + row] = vv[j];
        }
        __syncthreads();

        // S = Q K^T : 4 col-subtiles x 2 d-halves
        ffrag s[4];
        #pragma unroll
        for (int j = 0; j < 4; j++) {
            ffrag z = {0.f, 0.f, 0.f, 0.f};
            bfrag kf0 = *(const bfrag*)&Ks[(j * 16 + cl) * APAD + (qd << 3)];
            bfrag kf1 = *(const bfrag*)&Ks[(j * 16 + cl) * APAD + 32 + (qd << 3)];
            z = __builtin_amdgcn_mfma_f32_16x16x32_bf16(qf0, kf0, z, 0, 0, 0);
            z = __builtin_amdgcn_mfma_f32_16x16x32_bf16(qf1, kf1, z, 0, 0, 0);
            s[j] = z;
        }

        // mask (LOCAL masked out) + scale; C-layout: col = k0+j*16+cl, row = qd*4+r
        #pragma unroll
        for (int j = 0; j < 4; j++) {
            int kg = k0 + j * 16 + cl;
            int kr = kg / GG, kc = kg % GG;
            #pragma unroll
            for (int r = 0; r < 4; r++) {
                bool masked = (kg >= TT) ||
                              (abs(qr_[r] - kr) <= 4 && abs(qc_[r] - kc) <= 4);
                s[j][r] = masked ? -3.0e38f : s[j][r] * 0.125f;
            }
        }

        // online softmax (rows live in 16-lane groups sharing qd)
        float p_[4][4];
        #pragma unroll
        for (int r = 0; r < 4; r++) {
            float mx = fmaxf(fmaxf(s[0][r], s[1][r]), fmaxf(s[2][r], s[3][r]));
            mx = fmaxf(mx, __shfl_xor(mx, 1, 64));
            mx = fmaxf(mx, __shfl_xor(mx, 2, 64));
            mx = fmaxf(mx, __shfl_xor(mx, 4, 64));
            mx = fmaxf(mx, __shfl_xor(mx, 8, 64));
            float m_new = fmaxf(m_run[r], mx);
            float alpha = __expf(m_run[r] - m_new);
            float rs = 0.f;
            #pragma unroll
            for (int j = 0; j < 4; j++) {
                float pv = __expf(s[j][r] - m_new);
                p_[j][r] = pv;
                rs += pv;
            }
            rs += __shfl_xor(rs, 1, 64);
            rs += __shfl_xor(rs, 2, 64);
            rs += __shfl_xor(rs, 4, 64);
            rs += __shfl_xor(rs, 8, 64);
            l_run[r] = l_run[r] * alpha + rs;
            m_run[r] = m_new;
            #pragma unroll
            for (int t = 0; t < 4; t++) o_acc[t][r] *= alpha;
        }

        // P (C-layout) -> LDS rows (wave-private) for A-operand reuse
        #pragma unroll
        for (int j = 0; j < 4; j++)
            #pragma unroll
            for (int r = 0; r < 4; r++)
                Pb[(wave * 16 + (qd << 2) + r) * APAD + j * 16 + cl] = f2b(p_[j][r]);
        __syncthreads();   // within-wave LDS write->read ordering safety

        // O += P @ V : A = Pb rows (m = cl), B = Vt rows (n = d)
        bfrag pf0 = *(const bfrag*)&Pb[(wave * 16 + cl) * APAD + (qd << 3)];
        bfrag pf1 = *(const bfrag*)&Pb[(wave * 16 + cl) * APAD + 32 + (qd << 3)];
        #pragma unroll
        for (int t = 0; t < 4; t++) {
            bfrag vf0 = *(const bfrag*)&Vt[(t * 16 + cl) * APAD + (qd << 3)];
            bfrag vf1 = *(const bfrag*)&Vt[(t * 16 + cl) * APAD + 32 + (qd << 3)];
            o_acc[t] = __builtin_amdgcn_mfma_f32_16x16x32_bf16(pf0, vf0, o_acc[t], 0, 0, 0);
            o_acc[t] = __builtin_amdgcn_mfma_f32_16x16x32_bf16(pf1, vf1, o_acc[t], 0, 0, 0);
        }
    }

    #pragma unroll
    for (int r = 0; r < 4; r++) {
        if (qg_[r] < TT) {
            float inv = 1.0f / fmaxf(l_run[r], 1e-30f);
            #pragma unroll
            for (int t = 0; t < 4; t++)
                O[(size_t)(b * TT + qg_[r]) * EE + hh * 64 + t * 16 + cl] =
                    f2b(o_acc[t][r] * inv);
        }
    }
}

// ---------------------------------------------------------------- head
__global__ __launch_bounds__(256) void head_kernel(const float* __restrict__ Y,
                                                   const float* __restrict__ hw,
                                                   const float* __restrict__ hb,
                                                   const float* __restrict__ mean_,
                                                   const float* __restrict__ std_,
                                                   float* __restrict__ out) {
    __shared__ float sb[4];
    int row = blockIdx.x;
    int tid = threadIdx.x;
    const float* y = Y + (size_t)row * EE;
    float v = y[tid] * hw[tid] + y[tid + 256] * hw[tid + 256] + y[tid + 512] * hw[tid + 512];
    v = block_reduce_sum256(v, sb);
    if (tid == 0) {
        float logit = v + hb[0];
        float z = logit * std_[0] + mean_[0];
        float f = expf(z * 2.302585092994046f) - 1e-8f;
        f = fminf(fmaxf(f, 1e-15f), 1.0f);
        out[4 + row] = f;
    }
}

__global__ __launch_bounds__(256) void flux_sum_kernel(float* __restrict__ out) {
    __shared__ float sb[4];
    int b = blockIdx.x;
    int tid = threadIdx.x;
    const float* pf = out + 4 + (size_t)b * TT;
    float v = pf[tid] + pf[tid + 256] + pf[tid + 512];
    if (tid < TT - 768) v += pf[tid + 768];
    v = block_reduce_sum256(v, sb);
    if (tid == 0) out[b] = fmaxf(v, 1e-15f);
}

// ---------------------------------------------------------------- host
extern "C" void kernel_launch(void* const* d_in, const int* in_sizes, int n_in,
                              void* d_out, int out_size, void* d_ws, size_t ws_size,
                              hipStream_t stream) {
    const float* x        = (const float*)d_in[0];
    const float* sxr_mean = (const float*)d_in[1];
    const float* sxr_std  = (const float*)d_in[2];
    const float* input_w  = (const float*)d_in[3];
    const float* input_b  = (const float*)d_in[4];
    const float* pos_emb  = (const float*)d_in[5];
    const float* ln1_w    = (const float*)d_in[6];
    const float* ln1_b    = (const float*)d_in[7];
    const float* in_w     = (const float*)d_in[8];
    const float* in_b     = (const float*)d_in[9];
    const float* out_w    = (const float*)d_in[10];
    const float* out_b    = (const float*)d_in[11];
    const float* ln2_w    = (const float*)d_in[12];
    const float* ln2_b    = (const float*)d_in[13];
    const float* w1       = (const float*)d_in[14];
    const float* b1       = (const float*)d_in[15];
    const float* w2       = (const float*)d_in[16];
    const float* b2       = (const float*)d_in[17];
    const float* head_ln_w = (const float*)d_in[18];
    const float* head_ln_b = (const float*)d_in[19];
    const float* head_w   = (const float*)d_in[20];
    const float* head_b   = (const float*)d_in[21];
    float* out = (float*)d_out;

    const size_t NROW = (size_t)BB * TT;               // 3136
    const size_t NE   = NROW * EE;

    float* h   = (float*)d_ws;                         // [3136,768] f32
    float* y32 = h + NE;                               // [3136,768] f32 (head only)
    unsigned short* qkv_b = (unsigned short*)(y32 + NE);   // [3136,2304] bf16
    unsigned short* y_b   = qkv_b + NROW * 3 * EE;
    unsigned short* o_b   = y_b + NE;
    unsigned short* mlp_b = o_b + NE;                  // [3136,3072] bf16
    unsigned short* wq_b  = mlp_b + NROW * HDIM;
    unsigned short* wo_b  = wq_b + (size_t)3 * EE * EE;
    unsigned short* w1_b  = wo_b + (size_t)EE * EE;
    unsigned short* w2_b  = w1_b + (size_t)HDIM * EE;

    const int tot = BB * TT * EE;
    const int GY = (int)((NROW + 127) / 128);          // 25

    patchify_kernel<<<(tot + 255) / 256, 256, 0, stream>>>(x, mlp_b);
    cast_kernel<<<(EE * EE / 4 + 255) / 256, 256, 0, stream>>>(input_w, wo_b, EE * EE / 4);
    gemm_bf16<<<dim3(EE / 128, GY), 256, 0, stream>>>(
        mlp_b, wo_b, input_b, nullptr, h, nullptr, (int)NROW, EE, EE, 0);
    addpos_kernel<<<(tot + 255) / 256, 256, 0, stream>>>(h, pos_emb);

    for (int l = 0; l < NLAYER; l++) {
        cast_kernel<<<(3 * EE * EE / 4 + 255) / 256, 256, 0, stream>>>(
            in_w + (size_t)l * 3 * EE * EE, wq_b, 3 * EE * EE / 4);
        cast_kernel<<<(EE * EE / 4 + 255) / 256, 256, 0, stream>>>(
            out_w + (size_t)l * EE * EE, wo_b, EE * EE / 4);
        cast_kernel<<<(HDIM * EE / 4 + 255) / 256, 256, 0, stream>>>(
            w1 + (size_t)l * HDIM * EE, w1_b, HDIM * EE / 4);
        cast_kernel<<<(EE * HDIM / 4 + 255) / 256, 256, 0, stream>>>(
            w2 + (size_t)l * EE * HDIM, w2_b, EE * HDIM / 4);

        ln_kernel<<<(int)NROW, 256, 0, stream>>>(h, ln1_w + l * EE, ln1_b + l * EE, y_b, nullptr);
        gemm_bf16<<<dim3(3 * EE / 128, GY), 256, 0, stream>>>(
            y_b, wq_b, in_b + (size_t)l * 3 * EE, nullptr, nullptr, qkv_b,
            (int)NROW, 3 * EE, EE, 0);
        attn_kernel<<<dim3(13, BB * NHEAD), 256, 0, stream>>>(qkv_b, o_b);
        gemm_bf16<<<dim3(EE / 128, GY), 256, 0, stream>>>(
            o_b, wo_b, out_b + (size_t)l * EE, h, h, nullptr,
            (int)NROW, EE, EE, 0);
        ln_kernel<<<(int)NROW, 256, 0, stream>>>(h, ln2_w + l * EE, ln2_b + l * EE, y_b, nullptr);
        gemm_bf16<<<dim3(HDIM / 128, GY), 256, 0, stream>>>(
            y_b, w1_b, b1 + (size_t)l * HDIM, nullptr, nullptr, mlp_b,
            (int)NROW, HDIM, EE, 1);
        gemm_bf16<<<dim3(EE / 128, GY), 256, 0, stream>>>(
            mlp_b, w2_b, b2 + (size_t)l * EE, h, h, nullptr,
            (int)NROW, EE, HDIM, 0);
    }

    ln_kernel<<<(int)NROW, 256, 0, stream>>>(h, head_ln_w, head_ln_b, y_b, y32);
    head_kernel<<<(int)NROW, 256, 0, stream>>>(y32, head_w, head_b, sxr_mean, sxr_std, out);
    flux_sum_kernel<<<BB, 256, 0, stream>>>(out);
}

// Round 4
// 1752.572 us; speedup vs baseline: 3.0455x; 1.1827x over previous
//
#include <hip/hip_runtime.h>
#include <math.h>

#define BB 4
#define TT 784
#define GG 28
#define EE 768
#define HDIM 3072
#define NHEAD 12
#define NLAYER 6

typedef short bfrag __attribute__((ext_vector_type(8)));   // 8 bf16 = 4 VGPRs
typedef float ffrag __attribute__((ext_vector_type(4)));   // 4 fp32 acc

__device__ __forceinline__ unsigned short f2b(float f) {
    union { float f; unsigned u; } v; v.f = f;
    unsigned r = v.u + 0x7FFF + ((v.u >> 16) & 1);         // RNE
    return (unsigned short)(r >> 16);
}

#define GLOAD_LDS16(g, l)                                                          \
    __builtin_amdgcn_global_load_lds(                                              \
        (const __attribute__((address_space(1))) void*)(g),                        \
        (__attribute__((address_space(3))) void*)(l), 16, 0, 0)

// ---------------------------------------------------------------- reductions
__device__ __forceinline__ float block_reduce_sum256(float v, volatile float* sb) {
    #pragma unroll
    for (int m = 1; m < 64; m <<= 1) v += __shfl_xor(v, m, 64);
    int wave = threadIdx.x >> 6;
    if ((threadIdx.x & 63) == 0) sb[wave] = v;
    __syncthreads();
    return sb[0] + sb[1] + sb[2] + sb[3];
}

// ---------------------------------------------------------------- fp32 -> bf16 cast
__global__ __launch_bounds__(256) void cast_kernel(const float* __restrict__ s,
                                                   unsigned short* __restrict__ d, int n4) {
    int i = blockIdx.x * 256 + threadIdx.x;
    if (i >= n4) return;
    float4 v = ((const float4*)s)[i];
    ushort4 o;
    o.x = f2b(v.x); o.y = f2b(v.y); o.z = f2b(v.z); o.w = f2b(v.w);
    ((ushort4*)d)[i] = o;
}

// ---------------------------------------------------------------- fused per-layer weight cast (4 arrays, 1 launch)
// group counts (float4 units): in_w 442368 | out_w 147456 | w1 589824 | w2 589824
__global__ __launch_bounds__(256) void fused_cast_kernel(const float* __restrict__ iw,
                                                         const float* __restrict__ ow,
                                                         const float* __restrict__ W1,
                                                         const float* __restrict__ W2,
                                                         unsigned short* __restrict__ dq,
                                                         unsigned short* __restrict__ doo,
                                                         unsigned short* __restrict__ d1,
                                                         unsigned short* __restrict__ d2) {
    int i = blockIdx.x * 256 + threadIdx.x;
    const float* s; unsigned short* d; int k;
    if (i < 442368)            { s = iw;  d = dq;  k = i; }
    else if (i < 589824)       { s = ow;  d = doo; k = i - 442368; }
    else if (i < 1179648)      { s = W1;  d = d1;  k = i - 589824; }
    else if (i < 1769472)      { s = W2;  d = d2;  k = i - 1179648; }
    else return;
    float4 v = ((const float4*)s)[k];
    ushort4 o;
    o.x = f2b(v.x); o.y = f2b(v.y); o.z = f2b(v.z); o.w = f2b(v.w);
    ((ushort4*)d)[k] = o;
}

// ---------------------------------------------------------------- patchify -> bf16
__global__ __launch_bounds__(256) void patchify_kernel(const float* __restrict__ x,
                                                       unsigned short* __restrict__ P) {
    int idx = blockIdx.x * blockDim.x + threadIdx.x;
    const int total = BB * TT * EE;
    if (idx >= total) return;
    int k = idx % EE;
    int t = (idx / EE) % TT;
    int b = idx / (EE * TT);
    int c = k >> 8;
    int rem = k & 255;
    int p1 = rem >> 4;
    int p2 = rem & 15;
    int g1 = t / GG, g2 = t % GG;
    int hh = g1 * 16 + p1, ww = g2 * 16 + p2;
    P[idx] = f2b(x[((b * 448 + hh) * 448 + ww) * 3 + c]);
}

// ---------------------------------------------------------------- pos prefill (h = pos broadcast over batch)
__global__ __launch_bounds__(256) void posfill_kernel(float* __restrict__ h,
                                                      const float* __restrict__ pos) {
    int idx = blockIdx.x * blockDim.x + threadIdx.x;
    const int total = BB * TT * EE;
    if (idx >= total) return;
    h[idx] = pos[idx % (TT * EE)];
}

// ---------------------------------------------------------------- layernorm: fp32 in, bf16 out (+opt fp32)
__global__ __launch_bounds__(256) void ln_kernel(const float* __restrict__ X,
                                                 const float* __restrict__ g,
                                                 const float* __restrict__ bt,
                                                 unsigned short* __restrict__ Yb,
                                                 float* Yf) {
    __shared__ float sb1[4];
    __shared__ float sb2[4];
    int row = blockIdx.x;
    int tid = threadIdx.x;
    const float* x = X + (size_t)row * EE;
    float v0 = x[tid], v1 = x[tid + 256], v2 = x[tid + 512];
    float s = block_reduce_sum256(v0 + v1 + v2, sb1);
    float mean = s * (1.0f / 768.0f);
    float d0 = v0 - mean, d1 = v1 - mean, d2 = v2 - mean;
    __syncthreads();
    float ss = block_reduce_sum256(d0 * d0 + d1 * d1 + d2 * d2, sb2);
    float rstd = rsqrtf(ss * (1.0f / 768.0f) + 1e-5f);
    float y0 = d0 * rstd * g[tid]       + bt[tid];
    float y1 = d1 * rstd * g[tid + 256] + bt[tid + 256];
    float y2 = d2 * rstd * g[tid + 512] + bt[tid + 512];
    unsigned short* yb = Yb + (size_t)row * EE;
    yb[tid] = f2b(y0); yb[tid + 256] = f2b(y1); yb[tid + 512] = f2b(y2);
    if (Yf) {
        float* yf = Yf + (size_t)row * EE;
        yf[tid] = y0; yf[tid + 256] = y1; yf[tid + 512] = y2;
    }
}

// ---------------------------------------------------------------- bf16 MFMA GEMM (m97-style, non-split)
__global__ __launch_bounds__(256) void gemm_bf16(const unsigned short* __restrict__ A,
                                                 const unsigned short* __restrict__ W,
                                                 const float* __restrict__ bias,
                                                 const float* R, float* C,
                                                 unsigned short* Cb,
                                                 int M, int N, int K, int act) {
    __shared__ unsigned short As[128 * 32];
    __shared__ unsigned short Ws[128 * 32];
    int tid = threadIdx.x;
    int wave = tid >> 6, lane = tid & 63;
    int m0 = blockIdx.y << 7, n0 = blockIdx.x << 7;
    int mh = (wave & 1) << 6, nh = (wave >> 1) << 6;

    int cl = lane & 15, qd = lane >> 4;
    int sr = lane >> 2;
    int sc = (lane & 3) << 3;

    const unsigned short* Ap[2];
    const unsigned short* Wp[2];
    unsigned short* lA[2];
    unsigned short* lW[2];
    #pragma unroll
    for (int i = 0; i < 2; i++) {
        int ar = m0 + (wave << 5) + (i << 4) + sr;
        if (ar > M - 1) ar = M - 1;
        Ap[i] = A + (size_t)ar * K + sc;
        int wr = n0 + (wave << 5) + (i << 4) + sr;
        Wp[i] = W + (size_t)wr * K + sc;
        lA[i] = &As[((wave << 5) + (i << 4)) << 5];
        lW[i] = &Ws[((wave << 5) + (i << 4)) << 5];
    }

    ffrag acc[4][4] = {};

    for (int k0 = 0; k0 < K; k0 += 32) {
        __syncthreads();
        GLOAD_LDS16(Ap[0] + k0, lA[0]);
        GLOAD_LDS16(Ap[1] + k0, lA[1]);
        GLOAD_LDS16(Wp[0] + k0, lW[0]);
        GLOAD_LDS16(Wp[1] + k0, lW[1]);
        __syncthreads();

        bfrag af[4], bfr[4];
        #pragma unroll
        for (int i = 0; i < 4; i++)
            af[i] = *(const bfrag*)&As[(((mh + (i << 4) + cl)) << 5) + (qd << 3)];
        #pragma unroll
        for (int j = 0; j < 4; j++)
            bfr[j] = *(const bfrag*)&Ws[(((nh + (j << 4) + cl)) << 5) + (qd << 3)];
        #pragma unroll
        for (int i = 0; i < 4; i++)
            #pragma unroll
            for (int j = 0; j < 4; j++)
                acc[i][j] = __builtin_amdgcn_mfma_f32_16x16x32_bf16(af[i], bfr[j], acc[i][j], 0, 0, 0);
    }

    #pragma unroll
    for (int j = 0; j < 4; j++) {
        int col = n0 + nh + (j << 4) + cl;
        float bv = bias[col];
        #pragma unroll
        for (int i = 0; i < 4; i++) {
            int row0 = m0 + mh + (i << 4) + (qd << 2);
            #pragma unroll
            for (int r = 0; r < 4; r++) {
                int row = row0 + r;
                if (row < M) {
                    float v = acc[i][j][r] + bv;
                    if (R) v += R[(size_t)row * N + col];
                    if (act) v = 0.5f * v * (1.0f + erff(v * 0.70710678118654752f));
                    if (C)  C[(size_t)row * N + col] = v;
                    if (Cb) Cb[(size_t)row * N + col] = f2b(v);
                }
            }
        }
    }
}

// ---------------------------------------------------------------- split-K bf16 MFMA GEMM, atomic fp32 accumulate
// C += A@W^T (+bias on z==0 chunk). gridDim.z = SK, chunk length KC.
__global__ __launch_bounds__(256) void gemm_bf16_sk(const unsigned short* __restrict__ A,
                                                    const unsigned short* __restrict__ W,
                                                    const float* __restrict__ bias,
                                                    float* C,
                                                    int M, int N, int K, int KC) {
    __shared__ unsigned short As[128 * 32];
    __shared__ unsigned short Ws[128 * 32];
    int tid = threadIdx.x;
    int wave = tid >> 6, lane = tid & 63;
    int m0 = blockIdx.y << 7, n0 = blockIdx.x << 7;
    int mh = (wave & 1) << 6, nh = (wave >> 1) << 6;
    int z = blockIdx.z;
    int kbeg = z * KC;
    int kend = kbeg + KC > K ? K : kbeg + KC;

    int cl = lane & 15, qd = lane >> 4;
    int sr = lane >> 2;
    int sc = (lane & 3) << 3;

    const unsigned short* Ap[2];
    const unsigned short* Wp[2];
    unsigned short* lA[2];
    unsigned short* lW[2];
    #pragma unroll
    for (int i = 0; i < 2; i++) {
        int ar = m0 + (wave << 5) + (i << 4) + sr;
        if (ar > M - 1) ar = M - 1;
        Ap[i] = A + (size_t)ar * K + sc;
        int wr = n0 + (wave << 5) + (i << 4) + sr;
        Wp[i] = W + (size_t)wr * K + sc;
        lA[i] = &As[((wave << 5) + (i << 4)) << 5];
        lW[i] = &Ws[((wave << 5) + (i << 4)) << 5];
    }

    ffrag acc[4][4] = {};

    for (int k0 = kbeg; k0 < kend; k0 += 32) {
        __syncthreads();
        GLOAD_LDS16(Ap[0] + k0, lA[0]);
        GLOAD_LDS16(Ap[1] + k0, lA[1]);
        GLOAD_LDS16(Wp[0] + k0, lW[0]);
        GLOAD_LDS16(Wp[1] + k0, lW[1]);
        __syncthreads();

        bfrag af[4], bfr[4];
        #pragma unroll
        for (int i = 0; i < 4; i++)
            af[i] = *(const bfrag*)&As[(((mh + (i << 4) + cl)) << 5) + (qd << 3)];
        #pragma unroll
        for (int j = 0; j < 4; j++)
            bfr[j] = *(const bfrag*)&Ws[(((nh + (j << 4) + cl)) << 5) + (qd << 3)];
        #pragma unroll
        for (int i = 0; i < 4; i++)
            #pragma unroll
            for (int j = 0; j < 4; j++)
                acc[i][j] = __builtin_amdgcn_mfma_f32_16x16x32_bf16(af[i], bfr[j], acc[i][j], 0, 0, 0);
    }

    #pragma unroll
    for (int j = 0; j < 4; j++) {
        int col = n0 + nh + (j << 4) + cl;
        float bv = (z == 0) ? bias[col] : 0.0f;
        #pragma unroll
        for (int i = 0; i < 4; i++) {
            int row0 = m0 + mh + (i << 4) + (qd << 2);
            #pragma unroll
            for (int r = 0; r < 4; r++) {
                int row = row0 + r;
                if (row < M)
                    unsafeAtomicAdd(&C[(size_t)row * N + col], acc[i][j][r] + bv);
            }
        }
    }
}

// ---------------------------------------------------------------- MFMA flash attention, local-mask (masked OUT)
#define APAD 72
__global__ __launch_bounds__(256) void attn_kernel(const unsigned short* __restrict__ qkv,
                                                   unsigned short* __restrict__ O) {
    __shared__ unsigned short Ks[64 * APAD];
    __shared__ unsigned short Vt[64 * APAD];
    __shared__ unsigned short Pb[64 * APAD];
    int tid = threadIdx.x;
    int wave = tid >> 6, lane = tid & 63;
    int cl = lane & 15, qd = lane >> 4;
    int bh = blockIdx.y;
    int b = bh / NHEAD, hh = bh % NHEAD;
    int q0 = blockIdx.x * 64;

    int qrow = q0 + wave * 16 + cl;
    if (qrow > TT - 1) qrow = TT - 1;
    const unsigned short* qbase = qkv + (size_t)(b * TT + qrow) * 2304 + hh * 64;
    bfrag qf0 = *(const bfrag*)(qbase + (qd << 3));
    bfrag qf1 = *(const bfrag*)(qbase + 32 + (qd << 3));

    ffrag o_acc[4] = {};
    float m_run[4], l_run[4];
    int qg_[4], qr_[4], qc_[4];
    #pragma unroll
    for (int r = 0; r < 4; r++) {
        qg_[r] = q0 + wave * 16 + (qd << 2) + r;
        qr_[r] = qg_[r] / GG;
        qc_[r] = qg_[r] % GG;
        m_run[r] = -1e30f; l_run[r] = 0.0f;
    }

    int srow = tid >> 3;
    int sd = (tid & 7) << 3;

    for (int k0 = 0; k0 < 832; k0 += 64) {
        __syncthreads();
        #pragma unroll
        for (int it = 0; it < 2; it++) {
            int row = it * 32 + srow;
            int kg = k0 + row;
            int kgc = kg > TT - 1 ? TT - 1 : kg;
            const unsigned short* kb = qkv + (size_t)(b * TT + kgc) * 2304 + 768 + hh * 64 + sd;
            bfrag kv = *(const bfrag*)kb;
            *(bfrag*)&Ks[row * APAD + sd] = kv;
            bfrag vv = *(const bfrag*)(kb + 768);
            #pragma unroll
            for (int j = 0; j < 8; j++)
                Vt[(sd + j) * APAD + row] = vv[j];
        }
        __syncthreads();

        ffrag s[4];
        #pragma unroll
        for (int j = 0; j < 4; j++) {
            ffrag z = {0.f, 0.f, 0.f, 0.f};
            bfrag kf0 = *(const bfrag*)&Ks[(j * 16 + cl) * APAD + (qd << 3)];
            bfrag kf1 = *(const bfrag*)&Ks[(j * 16 + cl) * APAD + 32 + (qd << 3)];
            z = __builtin_amdgcn_mfma_f32_16x16x32_bf16(qf0, kf0, z, 0, 0, 0);
            z = __builtin_amdgcn_mfma_f32_16x16x32_bf16(qf1, kf1, z, 0, 0, 0);
            s[j] = z;
        }

        #pragma unroll
        for (int j = 0; j < 4; j++) {
            int kg = k0 + j * 16 + cl;
            int kr = kg / GG, kc = kg % GG;
            #pragma unroll
            for (int r = 0; r < 4; r++) {
                bool masked = (kg >= TT) ||
                              (abs(qr_[r] - kr) <= 4 && abs(qc_[r] - kc) <= 4);
                s[j][r] = masked ? -3.0e38f : s[j][r] * 0.125f;
            }
        }

        float p_[4][4];
        #pragma unroll
        for (int r = 0; r < 4; r++) {
            float mx = fmaxf(fmaxf(s[0][r], s[1][r]), fmaxf(s[2][r], s[3][r]));
            mx = fmaxf(mx, __shfl_xor(mx, 1, 64));
            mx = fmaxf(mx, __shfl_xor(mx, 2, 64));
            mx = fmaxf(mx, __shfl_xor(mx, 4, 64));
            mx = fmaxf(mx, __shfl_xor(mx, 8, 64));
            float m_new = fmaxf(m_run[r], mx);
            float alpha = __expf(m_run[r] - m_new);
            float rs = 0.f;
            #pragma unroll
            for (int j = 0; j < 4; j++) {
                float pv = __expf(s[j][r] - m_new);
                p_[j][r] = pv;
                rs += pv;
            }
            rs += __shfl_xor(rs, 1, 64);
            rs += __shfl_xor(rs, 2, 64);
            rs += __shfl_xor(rs, 4, 64);
            rs += __shfl_xor(rs, 8, 64);
            l_run[r] = l_run[r] * alpha + rs;
            m_run[r] = m_new;
            #pragma unroll
            for (int t = 0; t < 4; t++) o_acc[t][r] *= alpha;
        }

        #pragma unroll
        for (int j = 0; j < 4; j++)
            #pragma unroll
            for (int r = 0; r < 4; r++)
                Pb[(wave * 16 + (qd << 2) + r) * APAD + j * 16 + cl] = f2b(p_[j][r]);
        __syncthreads();

        bfrag pf0 = *(const bfrag*)&Pb[(wave * 16 + cl) * APAD + (qd << 3)];
        bfrag pf1 = *(const bfrag*)&Pb[(wave * 16 + cl) * APAD + 32 + (qd << 3)];
        #pragma unroll
        for (int t = 0; t < 4; t++) {
            bfrag vf0 = *(const bfrag*)&Vt[(t * 16 + cl) * APAD + (qd << 3)];
            bfrag vf1 = *(const bfrag*)&Vt[(t * 16 + cl) * APAD + 32 + (qd << 3)];
            o_acc[t] = __builtin_amdgcn_mfma_f32_16x16x32_bf16(pf0, vf0, o_acc[t], 0, 0, 0);
            o_acc[t] = __builtin_amdgcn_mfma_f32_16x16x32_bf16(pf1, vf1, o_acc[t], 0, 0, 0);
        }
    }

    #pragma unroll
    for (int r = 0; r < 4; r++) {
        if (qg_[r] < TT) {
            float inv = 1.0f / fmaxf(l_run[r], 1e-30f);
            #pragma unroll
            for (int t = 0; t < 4; t++)
                O[(size_t)(b * TT + qg_[r]) * EE + hh * 64 + t * 16 + cl] =
                    f2b(o_acc[t][r] * inv);
        }
    }
}

// ---------------------------------------------------------------- head
__global__ __launch_bounds__(256) void head_kernel(const float* __restrict__ Y,
                                                   const float* __restrict__ hw,
                                                   const float* __restrict__ hb,
                                                   const float* __restrict__ mean_,
                                                   const float* __restrict__ std_,
                                                   float* __restrict__ out) {
    __shared__ float sb[4];
    int row = blockIdx.x;
    int tid = threadIdx.x;
    const float* y = Y + (size_t)row * EE;
    float v = y[tid] * hw[tid] + y[tid + 256] * hw[tid + 256] + y[tid + 512] * hw[tid + 512];
    v = block_reduce_sum256(v, sb);
    if (tid == 0) {
        float logit = v + hb[0];
        float z = logit * std_[0] + mean_[0];
        float f = expf(z * 2.302585092994046f) - 1e-8f;
        f = fminf(fmaxf(f, 1e-15f), 1.0f);
        out[4 + row] = f;
    }
}

__global__ __launch_bounds__(256) void flux_sum_kernel(float* __restrict__ out) {
    __shared__ float sb[4];
    int b = blockIdx.x;
    int tid = threadIdx.x;
    const float* pf = out + 4 + (size_t)b * TT;
    float v = pf[tid] + pf[tid + 256] + pf[tid + 512];
    if (tid < TT - 768) v += pf[tid + 768];
    v = block_reduce_sum256(v, sb);
    if (tid == 0) out[b] = fmaxf(v, 1e-15f);
}

// ---------------------------------------------------------------- host
extern "C" void kernel_launch(void* const* d_in, const int* in_sizes, int n_in,
                              void* d_out, int out_size, void* d_ws, size_t ws_size,
                              hipStream_t stream) {
    const float* x        = (const float*)d_in[0];
    const float* sxr_mean = (const float*)d_in[1];
    const float* sxr_std  = (const float*)d_in[2];
    const float* input_w  = (const float*)d_in[3];
    const float* input_b  = (const float*)d_in[4];
    const float* pos_emb  = (const float*)d_in[5];
    const float* ln1_w    = (const float*)d_in[6];
    const float* ln1_b    = (const float*)d_in[7];
    const float* in_w     = (const float*)d_in[8];
    const float* in_b     = (const float*)d_in[9];
    const float* out_w    = (const float*)d_in[10];
    const float* out_b    = (const float*)d_in[11];
    const float* ln2_w    = (const float*)d_in[12];
    const float* ln2_b    = (const float*)d_in[13];
    const float* w1       = (const float*)d_in[14];
    const float* b1       = (const float*)d_in[15];
    const float* w2       = (const float*)d_in[16];
    const float* b2       = (const float*)d_in[17];
    const float* head_ln_w = (const float*)d_in[18];
    const float* head_ln_b = (const float*)d_in[19];
    const float* head_w   = (const float*)d_in[20];
    const float* head_b   = (const float*)d_in[21];
    float* out = (float*)d_out;

    const size_t NROW = (size_t)BB * TT;               // 3136
    const size_t NE   = NROW * EE;

    float* h   = (float*)d_ws;                         // [3136,768] f32
    float* y32 = h + NE;                               // [3136,768] f32 (head only)
    unsigned short* qkv_b = (unsigned short*)(y32 + NE);   // [3136,2304] bf16
    unsigned short* y_b   = qkv_b + NROW * 3 * EE;
    unsigned short* o_b   = y_b + NE;
    unsigned short* mlp_b = o_b + NE;                  // [3136,3072] bf16
    unsigned short* wq_b  = mlp_b + NROW * HDIM;
    unsigned short* wo_b  = wq_b + (size_t)3 * EE * EE;
    unsigned short* w1_b  = wo_b + (size_t)EE * EE;
    unsigned short* w2_b  = w1_b + (size_t)HDIM * EE;

    const int tot = BB * TT * EE;
    const int GY = (int)((NROW + 127) / 128);          // 25

    // patch embed: h = pos ; h += patches @ input_w^T + bias  (SK=2)
    patchify_kernel<<<(tot + 255) / 256, 256, 0, stream>>>(x, mlp_b);
    cast_kernel<<<(EE * EE / 4 + 255) / 256, 256, 0, stream>>>(input_w, wo_b, EE * EE / 4);
    posfill_kernel<<<(tot + 255) / 256, 256, 0, stream>>>(h, pos_emb);
    gemm_bf16_sk<<<dim3(EE / 128, GY, 2), 256, 0, stream>>>(
        mlp_b, wo_b, input_b, h, (int)NROW, EE, EE, 384);

    for (int l = 0; l < NLAYER; l++) {
        fused_cast_kernel<<<6912, 256, 0, stream>>>(
            in_w + (size_t)l * 3 * EE * EE, out_w + (size_t)l * EE * EE,
            w1 + (size_t)l * HDIM * EE, w2 + (size_t)l * EE * HDIM,
            wq_b, wo_b, w1_b, w2_b);

        ln_kernel<<<(int)NROW, 256, 0, stream>>>(h, ln1_w + l * EE, ln1_b + l * EE, y_b, nullptr);
        gemm_bf16<<<dim3(3 * EE / 128, GY), 256, 0, stream>>>(
            y_b, wq_b, in_b + (size_t)l * 3 * EE, nullptr, nullptr, qkv_b,
            (int)NROW, 3 * EE, EE, 0);
        attn_kernel<<<dim3(13, BB * NHEAD), 256, 0, stream>>>(qkv_b, o_b);
        gemm_bf16_sk<<<dim3(EE / 128, GY, 2), 256, 0, stream>>>(
            o_b, wo_b, out_b + (size_t)l * EE, h, (int)NROW, EE, EE, 384);
        ln_kernel<<<(int)NROW, 256, 0, stream>>>(h, ln2_w + l * EE, ln2_b + l * EE, y_b, nullptr);
        gemm_bf16<<<dim3(HDIM / 128, GY), 256, 0, stream>>>(
            y_b, w1_b, b1 + (size_t)l * HDIM, nullptr, nullptr, mlp_b,
            (int)NROW, HDIM, EE, 1);
        gemm_bf16_sk<<<dim3(EE / 128, GY, 4), 256, 0, stream>>>(
            mlp_b, w2_b, b2 + (size_t)l * EE, h, (int)NROW, EE, HDIM, 768);
    }

    ln_kernel<<<(int)NROW, 256, 0, stream>>>(h, head_ln_w, head_ln_b, y_b, y32);
    head_kernel<<<(int)NROW, 256, 0, stream>>>(y32, head_w, head_b, sxr_mean, sxr_std, out);
    flux_sum_kernel<<<BB, 256, 0, stream>>>(out);
}